// Round 1
// baseline (201.377 us; speedup 1.0000x reference)
//
#include <hip/hip_runtime.h>

// AdaptiveAttention: softmax is shift-invariant along the reduced axis, so
// out = softmax(alpha * QK^T) @ V. Two kernels:
//  1) prepass: K -> fp16, V -> transposed bf16, into d_ws as per-(head,kt)
//     32KB blocks with XOR-swizzled 16B granules (conflict-free MFMA reads).
//  2) attention: BQ=128 (32 queries/wave, 2 query-halves) so every LDS
//     K/V fragment read feeds 2x the MFMAs. Double-buffered global_load_lds
//     staging, single-pass fp16 QK^T (fp16x fp16 is ~5x more accurate than
//     the old bf16 hi/lo x bf16 split AND half the MFMAs), unnormalized exp2
//     softmax (logits bounded ~|50| << fp32 exponent range), MFMA PV (bf16:
//     unnormalized p reaches ~2^40 which overflows fp16), divide by
//     per-query l in the epilogue.
// ws requirement: 32 heads * 32 ktiles * 32KB = 32 MB.

#define S_LEN 2048
#define HD    128
#define BQ    128
#define BK    64
#define NW    4
#define NT    (S_LEN / BK)   // 32 k-tiles
#define TILE_USH 16384       // 32KB per (head,kt): K 8192 | Vt 8192 ushorts

typedef __bf16    bf16x8 __attribute__((ext_vector_type(8)));
typedef __bf16    bf16x4 __attribute__((ext_vector_type(4)));
typedef _Float16  f16x8  __attribute__((ext_vector_type(8)));
typedef float     f32x4  __attribute__((ext_vector_type(4)));

__device__ __forceinline__ unsigned short f2bf(float x) {
  unsigned u = __builtin_bit_cast(unsigned, x);
  u = (u + 0x7FFFu + ((u >> 16) & 1u)) >> 16;   // RNE
  return (unsigned short)u;
}
__device__ __forceinline__ unsigned short f2h(float x) {
  _Float16 h = (_Float16)x;                      // v_cvt_f16_f32, RNE
  return __builtin_bit_cast(unsigned short, h);
}
__device__ __forceinline__ float fast_exp2(float x) {
#if __has_builtin(__builtin_amdgcn_exp2f)
  return __builtin_amdgcn_exp2f(x);
#else
  return exp2f(x);
#endif
}

// ---------- prepass: convert + transpose + swizzle into ws ----------
__global__ __launch_bounds__(256) void attn_prepass_kernel(
    const float* __restrict__ kg, const float* __restrict__ vg,
    unsigned short* __restrict__ ws) {
  const int blk  = blockIdx.x;          // head*32 + kt
  const int head = blk >> 5;
  const int kt   = blk & 31;
  const int tid  = threadIdx.x;
  const size_t hoff = (size_t)head * S_LEN * HD;
  const float* kp = kg + hoff + (size_t)kt * BK * HD;
  const float* vp = vg + hoff + (size_t)kt * BK * HD;
  unsigned short* wsK  = ws + (size_t)blk * TILE_USH;
  unsigned short* wsVt = wsK + 8192;

  // K (fp16): granule (key, ch) = dims [ch*8, ch*8+8) of row key.
  // slot = (ch&8) | ((ch&7) ^ (key&7))  -> conflict-free b128 fragment reads.
#pragma unroll
  for (int it = 0; it < 4; ++it) {
    int idx = it * 256 + tid;           // 0..1023
    int key = idx >> 4;
    int ch  = idx & 15;
    const float* src = kp + key * HD + ch * 8;
    float4 a = *(const float4*)src;
    float4 b = *(const float4*)(src + 4);
    float xs[8] = {a.x, a.y, a.z, a.w, b.x, b.y, b.z, b.w};
    union { unsigned short s[8]; uint4 v; } hi;
#pragma unroll
    for (int j = 0; j < 8; ++j) hi.s[j] = f2h(xs[j]);
    int slot = (ch & 8) | ((ch & 7) ^ (key & 7));
    *(uint4*)&wsK[key * 128 + slot * 8] = hi.v;
  }

  // V^T (bf16): granule (dim, ch) = keys [ch*8, ch*8+8) of column dim.
  // slot = ch ^ (dim&7).
#pragma unroll
  for (int it = 0; it < 4; ++it) {
    int idx = it * 256 + tid;           // 0..1023
    int ch  = idx >> 7;                 // 0..7
    int dim = idx & 127;
    union { unsigned short s[8]; uint4 v; } g;
#pragma unroll
    for (int j = 0; j < 8; ++j)
      g.s[j] = f2bf(vp[(size_t)(ch * 8 + j) * HD + dim]);
    int slot = ch ^ (dim & 7);
    *(uint4*)&wsVt[dim * 64 + slot * 8] = g.v;
  }
}

// ---------- attention ----------
__device__ __forceinline__ void stage_tile(const unsigned short* __restrict__ wt,
                                           unsigned short* dst, int tid, int w) {
  // 8 rounds x 256 lanes x 16B = 32KB. LDS dest is wave-uniform base (w*64
  // granules) + implicit lane*16B -- the m104/m108 requirement.
#pragma unroll
  for (int r = 0; r < 8; ++r) {
    const unsigned int* gp = (const unsigned int*)(wt + (size_t)(r * 256 + tid) * 8);
    unsigned short* lp = dst + (size_t)(r * 256 + w * 64) * 8;
    __builtin_amdgcn_global_load_lds(
        (const __attribute__((address_space(1))) unsigned int*)gp,
        (__attribute__((address_space(3))) unsigned int*)lp, 16, 0, 0);
  }
}

__global__ __launch_bounds__(256, 2) void adaptive_attn_kernel(
    const float* __restrict__ qg, const unsigned short* __restrict__ ws,
    const float* __restrict__ alphap, float* __restrict__ out) {
  __shared__ unsigned short sBuf[2][TILE_USH];   // 64 KB double buffer
  __shared__ unsigned short sP[NW][2][1024];     // 16 KB: per wave/half, XOR-swizzled
  // 80 KB total -> exactly 2 blocks/CU on 160KB LDS

  const int b    = blockIdx.x;                   // 512 blocks
  const int head = (b & 7) * 4 + ((b >> 3) & 3); // XCD L2 locality swizzle
  const int qt   = b >> 5;                       // 0..15

  const int tid  = threadIdx.x;
  const int w    = tid >> 6;
  const int lane = tid & 63;
  const int g    = lane >> 4;
  const int qi   = lane & 15;

  const float lscale = alphap[0] * 1.44269504088896f;  // alpha * log2(e)

  // Q fragments (B-operand layout) for both query halves, fp16(lscale*Q).
  f16x8 qf[2][4];
#pragma unroll
  for (int h = 0; h < 2; ++h) {
    const int qrow = qt * BQ + w * 32 + h * 16 + qi;
    const float* qp = qg + (size_t)head * S_LEN * HD + (size_t)qrow * HD;
#pragma unroll
    for (int c = 0; c < 4; ++c) {
      float4 a  = *(const float4*)(qp + c * 32 + g * 8);
      float4 bb = *(const float4*)(qp + c * 32 + g * 8 + 4);
      float xs[8] = {a.x, a.y, a.z, a.w, bb.x, bb.y, bb.z, bb.w};
      union { f16x8 v; _Float16 s[8]; } hh;
#pragma unroll
      for (int j = 0; j < 8; ++j) hh.s[j] = (_Float16)(xs[j] * lscale);
      qf[h][c] = hh.v;
    }
  }

  f32x4 o[2][8];
#pragma unroll
  for (int h = 0; h < 2; ++h)
#pragma unroll
    for (int dt = 0; dt < 8; ++dt) o[h][dt] = (f32x4){0.f, 0.f, 0.f, 0.f};
  float lrun[2] = {0.f, 0.f};

  const unsigned short* wsh = ws + (size_t)head * NT * TILE_USH;

  // Prologue: stage tile 0 into buffer 0.
  stage_tile(wsh, &sBuf[0][0], tid, w);
  __syncthreads();

  for (int kt = 0; kt < NT; ++kt) {
    const unsigned short* sK  = &sBuf[kt & 1][0];
    const unsigned short* sVt = sK + 8192;

    // Prefetch next tile; its vmcnt drain hides behind compute.
    if (kt + 1 < NT)
      stage_tile(wsh + (size_t)(kt + 1) * TILE_USH, &sBuf[(kt + 1) & 1][0], tid, w);

    // S^T (64 keys x 32 queries): each K fragment read feeds 2 MFMAs
    // (2 query halves). key&7 == qi&7 since key = mt*16+qi.
    f32x4 st[2][4];
#pragma unroll
    for (int mt = 0; mt < 4; ++mt) {
      f32x4 a0 = (f32x4){0.f, 0.f, 0.f, 0.f};
      f32x4 a1 = (f32x4){0.f, 0.f, 0.f, 0.f};
#pragma unroll
      for (int c = 0; c < 4; ++c) {
        int ch   = c * 4 + g;
        int slot = (ch & 8) | ((ch & 7) ^ (qi & 7));
        f16x8 ah = *(const f16x8*)&sK[(mt * 16 + qi) * 128 + slot * 8];
        a0 = __builtin_amdgcn_mfma_f32_16x16x32_f16(ah, qf[0][c], a0, 0, 0, 0);
        a1 = __builtin_amdgcn_mfma_f32_16x16x32_f16(ah, qf[1][c], a1, 0, 0, 0);
      }
      st[0][mt] = a0; st[1][mt] = a1;
    }

    // Unnormalized softmax: p = exp2(st) (bounded logits; /l at the end).
    // P^T -> A-layout via per-wave per-half XOR-swizzled LDS staging:
    // write granule gr = mt*2+(g>>1), sub = g&1, slot = gr ^ (qi&7).
#pragma unroll
    for (int h = 0; h < 2; ++h) {
      unsigned short* sPh = &sP[w][h][0];
#pragma unroll
      for (int mt = 0; mt < 4; ++mt) {
        float p0 = fast_exp2(st[h][mt][0]);
        float p1 = fast_exp2(st[h][mt][1]);
        float p2 = fast_exp2(st[h][mt][2]);
        float p3 = fast_exp2(st[h][mt][3]);
        lrun[h] += (p0 + p1) + (p2 + p3);
        bf16x4 pv4;
        pv4[0] = (__bf16)p0; pv4[1] = (__bf16)p1;
        pv4[2] = (__bf16)p2; pv4[3] = (__bf16)p3;
        int slot = (mt * 2 + (g >> 1)) ^ (qi & 7);
        *(bf16x4*)&sPh[qi * 64 + slot * 8 + (g & 1) * 4] = pv4;
      }
    }

    bf16x8 pf[2][2];
#pragma unroll
    for (int h = 0; h < 2; ++h)
#pragma unroll
      for (int c = 0; c < 2; ++c) {
        int slot = (c * 4 + g) ^ (qi & 7);   // read granule = c*4+g (8 keys)
        pf[h][c] = *(const bf16x8*)&sP[w][h][qi * 64 + slot * 8];
      }

    // PV: each V fragment read feeds 2 MFMAs (both query halves).
#pragma unroll
    for (int dt = 0; dt < 8; ++dt) {
      f32x4 a0 = o[0][dt];
      f32x4 a1 = o[1][dt];
#pragma unroll
      for (int c = 0; c < 2; ++c) {
        int slot = (c * 4 + g) ^ (qi & 7);   // dim&7 == qi&7
        bf16x8 vf = *(const bf16x8*)&sVt[(dt * 16 + qi) * 64 + slot * 8];
        a0 = __builtin_amdgcn_mfma_f32_16x16x32_bf16(pf[0][c], vf, a0, 0, 0, 0);
        a1 = __builtin_amdgcn_mfma_f32_16x16x32_bf16(pf[1][c], vf, a1, 0, 0, 0);
      }
      o[0][dt] = a0; o[1][dt] = a1;
    }

    // One barrier per iteration: (a) all reads of buf[kt&1] done before
    // iteration kt+1 prefetches kt+2 into it; (b) drains the kt+1 DMA.
    __syncthreads();
  }

  // Epilogue: reduce l across quads, divide, store fp32.
  float* oph = out + (size_t)head * S_LEN * HD + (size_t)(qt * BQ + w * 32) * HD;
#pragma unroll
  for (int h = 0; h < 2; ++h) {
    float ltot = lrun[h];
    ltot += __shfl_xor(ltot, 16, 64);
    ltot += __shfl_xor(ltot, 32, 64);  // lanes with same qi hold l(query qi)
    float inv[4];
#pragma unroll
    for (int r = 0; r < 4; ++r) {
      float lr = __shfl(ltot, g * 4 + r, 64);
      inv[r] = 1.0f / lr;
    }
    float* op = oph + (size_t)(h * 16) * HD;
#pragma unroll
    for (int dt = 0; dt < 8; ++dt) {
#pragma unroll
      for (int r = 0; r < 4; ++r) {
        op[(size_t)(g * 4 + r) * HD + dt * 16 + qi] = o[h][dt][r] * inv[r];
      }
    }
  }
}

extern "C" void kernel_launch(void* const* d_in, const int* in_sizes, int n_in,
                              void* d_out, int out_size, void* d_ws, size_t ws_size,
                              hipStream_t stream) {
  const float* q     = (const float*)d_in[0];
  const float* k     = (const float*)d_in[1];
  const float* v     = (const float*)d_in[2];
  const float* alpha = (const float*)d_in[3];
  float* out = (float*)d_out;
  unsigned short* ws = (unsigned short*)d_ws;   // needs 32 MB

  hipLaunchKernelGGL(attn_prepass_kernel, dim3(1024), dim3(256), 0, stream,
                     k, v, ws);
  hipLaunchKernelGGL(adaptive_attn_kernel, dim3(512), dim3(256), 0, stream,
                     q, ws, alpha, out);
}

// Round 2
// 200.831 us; speedup vs baseline: 1.0027x; 1.0027x over previous
//
#include <hip/hip_runtime.h>

// AdaptiveAttention: softmax is shift-invariant along the reduced axis, so
// out = softmax(alpha * QK^T) @ V. Two kernels:
//  1) prepass: K -> fp16, V -> transposed bf16 (via LDS-mediated transpose so
//     both global sides are coalesced), into d_ws as per-(head,kt) 32KB blocks
//     with XOR-swizzled 16B granules (conflict-free MFMA reads).
//  2) attention: BQ=128 (32 queries/wave, 2 query-halves). Double-buffered
//     global_load_lds staging, single-pass fp16 QK^T, unnormalized exp2
//     softmax, MFMA PV (bf16: unnormalized p reaches ~2^40 which overflows
//     fp16), divide by per-query l in the epilogue.
//     PIPELINED: PV runs one k-tile behind (V frags + P frags carried in
//     registers across the barrier), so PV(kt-1) MFMAs overlap softmax(kt)
//     VALU + the sP LDS round-trip instead of serializing. s_setprio(1)
//     around MFMA clusters (T5).
// ws requirement: 32 heads * 32 ktiles * 32KB = 32 MB.

#define S_LEN 2048
#define HD    128
#define BQ    128
#define BK    64
#define NW    4
#define NT    (S_LEN / BK)   // 32 k-tiles
#define TILE_USH 16384       // 32KB per (head,kt): K 8192 | Vt 8192 ushorts

typedef __bf16    bf16x8 __attribute__((ext_vector_type(8)));
typedef __bf16    bf16x4 __attribute__((ext_vector_type(4)));
typedef _Float16  f16x8  __attribute__((ext_vector_type(8)));
typedef float     f32x4  __attribute__((ext_vector_type(4)));

__device__ __forceinline__ unsigned short f2bf(float x) {
  unsigned u = __builtin_bit_cast(unsigned, x);
  u = (u + 0x7FFFu + ((u >> 16) & 1u)) >> 16;   // RNE
  return (unsigned short)u;
}
__device__ __forceinline__ unsigned short f2h(float x) {
  _Float16 h = (_Float16)x;                      // v_cvt_f16_f32, RNE
  return __builtin_bit_cast(unsigned short, h);
}
__device__ __forceinline__ float fast_exp2(float x) {
#if __has_builtin(__builtin_amdgcn_exp2f)
  return __builtin_amdgcn_exp2f(x);
#else
  return exp2f(x);
#endif
}

// ---------- prepass: convert + transpose + swizzle into ws ----------
__global__ __launch_bounds__(256) void attn_prepass_kernel(
    const float* __restrict__ kg, const float* __restrict__ vg,
    unsigned short* __restrict__ ws) {
  __shared__ float T[64 * 130];         // V staging, stride 130 (b64-aligned)
  const int blk  = blockIdx.x;          // head*32 + kt
  const int head = blk >> 5;
  const int kt   = blk & 31;
  const int tid  = threadIdx.x;
  const size_t hoff = (size_t)head * S_LEN * HD;
  const float* kp = kg + hoff + (size_t)kt * BK * HD;
  const float* vp = vg + hoff + (size_t)kt * BK * HD;
  unsigned short* wsK  = ws + (size_t)blk * TILE_USH;
  unsigned short* wsVt = wsK + 8192;

  // K (fp16): granule (key, ch) = dims [ch*8, ch*8+8) of row key.
  // slot = (ch&8) | ((ch&7) ^ (key&7))  -> conflict-free b128 fragment reads.
#pragma unroll
  for (int it = 0; it < 4; ++it) {
    int idx = it * 256 + tid;           // 0..1023
    int key = idx >> 4;
    int ch  = idx & 15;
    const float* src = kp + key * HD + ch * 8;
    float4 a = *(const float4*)src;
    float4 b = *(const float4*)(src + 4);
    float xs[8] = {a.x, a.y, a.z, a.w, b.x, b.y, b.z, b.w};
    union { unsigned short s[8]; uint4 v; } hi;
#pragma unroll
    for (int j = 0; j < 8; ++j) hi.s[j] = f2h(xs[j]);
    int slot = (ch & 8) | ((ch & 7) ^ (key & 7));
    *(uint4*)&wsK[key * 128 + slot * 8] = hi.v;
  }

  // V^T via LDS: phase 1 -- coalesced float2 loads, contiguous LDS row writes.
#pragma unroll
  for (int it = 0; it < 16; ++it) {
    int idx = it * 256 + tid;           // 0..4095 float2 granules
    int key = idx >> 6;                 // 64 float2 per row
    int c2  = idx & 63;
    float2 a = *(const float2*)(vp + (size_t)key * HD + c2 * 2);
    *(float2*)&T[key * 130 + c2 * 2] = a;
  }
  __syncthreads();

  // phase 2 -- column gather from LDS (<=4-way conflicts), coalesced 16B
  // granule writes: a wave covers 8 dims x 8 ch = contiguous 1KB of wsVt.
  // granule (dim, ch) = keys [ch*8, ch*8+8) of column dim; slot = ch^(dim&7).
#pragma unroll
  for (int r = 0; r < 4; ++r) {
    int idx = r * 256 + tid;            // 0..1023
    int dim = idx >> 3;                 // 0..127
    int ch  = idx & 7;
    union { unsigned short s[8]; uint4 v; } gg;
#pragma unroll
    for (int j = 0; j < 8; ++j) gg.s[j] = f2bf(T[(ch * 8 + j) * 130 + dim]);
    int slot = ch ^ (dim & 7);
    *(uint4*)&wsVt[dim * 64 + slot * 8] = gg.v;
  }
}

// ---------- attention ----------
__device__ __forceinline__ void stage_tile(const unsigned short* __restrict__ wt,
                                           unsigned short* dst, int tid, int w) {
  // 8 rounds x 256 lanes x 16B = 32KB. LDS dest is wave-uniform base (w*64
  // granules) + implicit lane*16B -- the m104/m108 requirement.
#pragma unroll
  for (int r = 0; r < 8; ++r) {
    const unsigned int* gp = (const unsigned int*)(wt + (size_t)(r * 256 + tid) * 8);
    unsigned short* lp = dst + (size_t)(r * 256 + w * 64) * 8;
    __builtin_amdgcn_global_load_lds(
        (const __attribute__((address_space(1))) unsigned int*)gp,
        (__attribute__((address_space(3))) unsigned int*)lp, 16, 0, 0);
  }
}

__global__ __launch_bounds__(256, 2) void adaptive_attn_kernel(
    const float* __restrict__ qg, const unsigned short* __restrict__ ws,
    const float* __restrict__ alphap, float* __restrict__ out) {
  __shared__ unsigned short sBuf[2][TILE_USH];   // 64 KB double buffer
  __shared__ unsigned short sP[NW][2][1024];     // 16 KB: per wave/half, XOR-swizzled
  // 80 KB total -> exactly 2 blocks/CU on 160KB LDS

  const int b    = blockIdx.x;                   // 512 blocks
  const int head = (b & 7) * 4 + ((b >> 3) & 3); // XCD L2 locality swizzle
  const int qt   = b >> 5;                       // 0..15

  const int tid  = threadIdx.x;
  const int w    = tid >> 6;
  const int lane = tid & 63;
  const int g    = lane >> 4;
  const int qi   = lane & 15;

  const float lscale = alphap[0] * 1.44269504088896f;  // alpha * log2(e)

  // Q fragments (B-operand layout) for both query halves, fp16(lscale*Q).
  f16x8 qf[2][4];
#pragma unroll
  for (int h = 0; h < 2; ++h) {
    const int qrow = qt * BQ + w * 32 + h * 16 + qi;
    const float* qp = qg + (size_t)head * S_LEN * HD + (size_t)qrow * HD;
#pragma unroll
    for (int c = 0; c < 4; ++c) {
      float4 a  = *(const float4*)(qp + c * 32 + g * 8);
      float4 bb = *(const float4*)(qp + c * 32 + g * 8 + 4);
      float xs[8] = {a.x, a.y, a.z, a.w, bb.x, bb.y, bb.z, bb.w};
      union { f16x8 v; _Float16 s[8]; } hh;
#pragma unroll
      for (int j = 0; j < 8; ++j) hh.s[j] = (_Float16)(xs[j] * lscale);
      qf[h][c] = hh.v;
    }
  }

  f32x4 o[2][8];
#pragma unroll
  for (int h = 0; h < 2; ++h)
#pragma unroll
    for (int dt = 0; dt < 8; ++dt) o[h][dt] = (f32x4){0.f, 0.f, 0.f, 0.f};
  float lrun[2] = {0.f, 0.f};

  // Pipeline registers: V fragments + P fragments of tile kt, consumed by
  // PV during iteration kt+1 (so PV overlaps softmax/QK^T of the next tile).
  bf16x8 vreg[8][2];
  bf16x8 pf[2][2];

  const unsigned short* wsh = ws + (size_t)head * NT * TILE_USH;

  // Prologue: stage tile 0 into buffer 0.
  stage_tile(wsh, &sBuf[0][0], tid, w);
  __syncthreads();

  for (int kt = 0; kt < NT; ++kt) {
    const unsigned short* sK  = &sBuf[kt & 1][0];
    const unsigned short* sVt = sK + 8192;

    // Prefetch next tile; its vmcnt drain hides behind compute.
    if (kt + 1 < NT)
      stage_tile(wsh + (size_t)(kt + 1) * TILE_USH, &sBuf[(kt + 1) & 1][0], tid, w);

    // S^T (64 keys x 32 queries): each K fragment read feeds 2 MFMAs
    // (2 query halves). key&7 == qi&7 since key = mt*16+qi.
    f32x4 st[2][4];
    __builtin_amdgcn_s_setprio(1);
#pragma unroll
    for (int mt = 0; mt < 4; ++mt) {
      f32x4 a0 = (f32x4){0.f, 0.f, 0.f, 0.f};
      f32x4 a1 = (f32x4){0.f, 0.f, 0.f, 0.f};
#pragma unroll
      for (int c = 0; c < 4; ++c) {
        int ch   = c * 4 + g;
        int slot = (ch & 8) | ((ch & 7) ^ (qi & 7));
        f16x8 ah = *(const f16x8*)&sK[(mt * 16 + qi) * 128 + slot * 8];
        a0 = __builtin_amdgcn_mfma_f32_16x16x32_f16(ah, qf[0][c], a0, 0, 0, 0);
        a1 = __builtin_amdgcn_mfma_f32_16x16x32_f16(ah, qf[1][c], a1, 0, 0, 0);
      }
      st[0][mt] = a0; st[1][mt] = a1;
    }
    __builtin_amdgcn_s_setprio(0);

    // PV(kt-1): independent of softmax(kt) below -- register-only MFMAs that
    // the scheduler interleaves with the exp2/VALU work and sP round trip.
    if (kt > 0) {
      __builtin_amdgcn_s_setprio(1);
#pragma unroll
      for (int dt = 0; dt < 8; ++dt) {
        f32x4 a0 = o[0][dt];
        f32x4 a1 = o[1][dt];
#pragma unroll
        for (int c = 0; c < 2; ++c) {
          a0 = __builtin_amdgcn_mfma_f32_16x16x32_bf16(pf[0][c], vreg[dt][c], a0, 0, 0, 0);
          a1 = __builtin_amdgcn_mfma_f32_16x16x32_bf16(pf[1][c], vreg[dt][c], a1, 0, 0, 0);
        }
        o[0][dt] = a0; o[1][dt] = a1;
      }
      __builtin_amdgcn_s_setprio(0);
    }

    // Unnormalized softmax: p = exp2(st) (bounded logits; /l at the end).
    // P^T -> A-layout via per-wave per-half XOR-swizzled LDS staging:
    // write granule gr = mt*2+(g>>1), sub = g&1, slot = gr ^ (qi&7).
#pragma unroll
    for (int h = 0; h < 2; ++h) {
      unsigned short* sPh = &sP[w][h][0];
#pragma unroll
      for (int mt = 0; mt < 4; ++mt) {
        float p0 = fast_exp2(st[h][mt][0]);
        float p1 = fast_exp2(st[h][mt][1]);
        float p2 = fast_exp2(st[h][mt][2]);
        float p3 = fast_exp2(st[h][mt][3]);
        lrun[h] += (p0 + p1) + (p2 + p3);
        bf16x4 pv4;
        pv4[0] = (__bf16)p0; pv4[1] = (__bf16)p1;
        pv4[2] = (__bf16)p2; pv4[3] = (__bf16)p3;
        int slot = (mt * 2 + (g >> 1)) ^ (qi & 7);
        *(bf16x4*)&sPh[qi * 64 + slot * 8 + (g & 1) * 4] = pv4;
      }
    }

    // P fragments for PV (consumed next iteration).
#pragma unroll
    for (int h = 0; h < 2; ++h)
#pragma unroll
      for (int c = 0; c < 2; ++c) {
        int slot = (c * 4 + g) ^ (qi & 7);   // read granule = c*4+g (8 keys)
        pf[h][c] = *(const bf16x8*)&sP[w][h][qi * 64 + slot * 8];
      }

    // V fragments of tile kt into registers (consumed next iteration). Reading
    // into regs keeps the LDS double buffer legal: V crosses the barrier in
    // registers, not in sBuf.
#pragma unroll
    for (int dt = 0; dt < 8; ++dt)
#pragma unroll
      for (int c = 0; c < 2; ++c) {
        int slot = (c * 4 + g) ^ (qi & 7);   // dim&7 == qi&7
        vreg[dt][c] = *(const bf16x8*)&sVt[(dt * 16 + qi) * 64 + slot * 8];
      }

    // One barrier per iteration: (a) all reads of buf[kt&1] done before
    // iteration kt+1 prefetches kt+2 into it; (b) drains the kt+1 DMA.
    __syncthreads();
  }

  // Drain the pipeline: PV for the last tile.
  __builtin_amdgcn_s_setprio(1);
#pragma unroll
  for (int dt = 0; dt < 8; ++dt) {
    f32x4 a0 = o[0][dt];
    f32x4 a1 = o[1][dt];
#pragma unroll
    for (int c = 0; c < 2; ++c) {
      a0 = __builtin_amdgcn_mfma_f32_16x16x32_bf16(pf[0][c], vreg[dt][c], a0, 0, 0, 0);
      a1 = __builtin_amdgcn_mfma_f32_16x16x32_bf16(pf[1][c], vreg[dt][c], a1, 0, 0, 0);
    }
    o[0][dt] = a0; o[1][dt] = a1;
  }
  __builtin_amdgcn_s_setprio(0);

  // Epilogue: reduce l across quads, divide, store fp32.
  float* oph = out + (size_t)head * S_LEN * HD + (size_t)(qt * BQ + w * 32) * HD;
#pragma unroll
  for (int h = 0; h < 2; ++h) {
    float ltot = lrun[h];
    ltot += __shfl_xor(ltot, 16, 64);
    ltot += __shfl_xor(ltot, 32, 64);  // lanes with same qi hold l(query qi)
    float inv[4];
#pragma unroll
    for (int r = 0; r < 4; ++r) {
      float lr = __shfl(ltot, g * 4 + r, 64);
      inv[r] = 1.0f / lr;
    }
    float* op = oph + (size_t)(h * 16) * HD;
#pragma unroll
    for (int dt = 0; dt < 8; ++dt) {
#pragma unroll
      for (int r = 0; r < 4; ++r) {
        op[(size_t)(g * 4 + r) * HD + dt * 16 + qi] = o[h][dt][r] * inv[r];
      }
    }
  }
}

extern "C" void kernel_launch(void* const* d_in, const int* in_sizes, int n_in,
                              void* d_out, int out_size, void* d_ws, size_t ws_size,
                              hipStream_t stream) {
  const float* q     = (const float*)d_in[0];
  const float* k     = (const float*)d_in[1];
  const float* v     = (const float*)d_in[2];
  const float* alpha = (const float*)d_in[3];
  float* out = (float*)d_out;
  unsigned short* ws = (unsigned short*)d_ws;   // needs 32 MB

  hipLaunchKernelGGL(attn_prepass_kernel, dim3(1024), dim3(256), 0, stream,
                     k, v, ws);
  hipLaunchKernelGGL(adaptive_attn_kernel, dim3(512), dim3(256), 0, stream,
                     q, ws, alpha, out);
}